// Round 11
// baseline (427.857 us; speedup 1.0000x reference)
//
#include <hip/hip_runtime.h>
#include <stdint.h>

typedef __attribute__((ext_vector_type(8))) short short8;
typedef __attribute__((ext_vector_type(4))) float f32x4;

constexpr int      BATCH    = 524288;
constexpr int      ARRAY_SZ = 262144;
constexpr uint64_t PRIME    = 2038074743ull;
constexpr uint32_t RANGE    = 262137u;          // ARRAY_SZ - 8 + 1
constexpr int      NMT      = BATCH / 16;       // 32768 M-tiles of 16 elements
constexpr int      TSTRIDE  = 136;              // T row stride (shorts), padded
constexpr int      PSTRIDE  = 68;               // pw row stride (dwords), padded
// Rigorous sign-certainty bound (round-10, absmax 0.0): flagged entries are
// recomputed with the sequential fmaf chain proven bit-exact in rounds 1-10.
constexpr float    EPS      = 8e-5f;

__global__ __launch_bounds__(256, 3)
void lma_mfma2(const float* __restrict__ x,
               const float* __restrict__ hw,
               const float* __restrict__ lsh,
               const void* __restrict__ rnd_raw,
               float* __restrict__ out_idx,   // B*128 floats (idx as f32)
               float* __restrict__ out_val)   // B*64 floats
{
    // T[n][i]: lsh transposed to bf16 (exact: values in {-1,0,1}); padded row
    // stride 136 shorts -> B-frag b128 reads land uniform on bank groups.
    __shared__ unsigned short T[128 * TSTRIDE];          // 34816 B
    // pw[wave][e][col<64]: per-wave proj transpose for one rep-half; padded.
    __shared__ float pw[4][16 * PSTRIDE];                // 17408 B

    const int tid  = threadIdx.x;
    const int lane = tid & 63;
    const int wid  = __builtin_amdgcn_readfirstlane(tid >> 6);

    // --- hash constants: detect int64 vs int32 layout of random_numbers ---
    uint64_t HA, HB, HC0;
    {
        const uint64_t first8 = *reinterpret_cast<const uint64_t*>(rnd_raw);
        if (first8 == PRIME) {
            const long long* r64 = reinterpret_cast<const long long*>(rnd_raw);
            HA = (uint64_t)r64[1]; HB = (uint64_t)r64[2]; HC0 = (uint64_t)r64[3];
        } else {
            const int* r32 = reinterpret_cast<const int*>(rnd_raw);
            HA  = (uint64_t)(uint32_t)r32[1];
            HB  = (uint64_t)(uint32_t)r32[2];
            HC0 = (uint64_t)(uint32_t)r32[3];
        }
    }

    // --- stage T = bf16(lsh)^T (one-time; bf16 of +-1/0 = high 16 bits) ---
    for (int it = 0; it < 16; ++it) {
        const int flat4 = it * 256 + tid;            // 0..4095
        const int i  = flat4 >> 5;                   // input dim 0..127
        const int n4 = (flat4 & 31) << 2;            // output col base
        const f32x4 v = *reinterpret_cast<const f32x4*>(lsh + i * 128 + n4);
#pragma unroll
        for (int d = 0; d < 4; ++d)
            T[(n4 + d) * TSTRIDE + i] =
                (unsigned short)(__float_as_uint(v[d]) >> 16);
    }
    __syncthreads();   // the only block-wide barrier; T is read-only after

    const int r  = lane & 15;         // A-operand M row / B-operand N col
    const int g  = lane >> 4;         // k-group
    const int e  = lane >> 2;         // phase-2 element (0..15)
    const int c4 = lane & 3;          // phase-2 chunk slot

    for (int mt = blockIdx.x * 4 + wid; mt < NMT; mt += 8192) {
        const int Mb = mt * 16;
        const float* xb = x + (size_t)Mb * 128;

        f32x4 acc[8];
#pragma unroll
        for (int n8 = 0; n8 < 8; ++n8) acc[n8] = (f32x4)(0.0f);
        float asum = 0.0f;

#pragma unroll
        for (int ks = 0; ks < 4; ++ks) {
            const float* xp = xb + r * 128 + ks * 32 + g * 8;
            const f32x4 xa = *reinterpret_cast<const f32x4*>(xp);
            const f32x4 xc = *reinterpret_cast<const f32x4*>(xp + 4);
            float xs[8] = {xa[0], xa[1], xa[2], xa[3], xc[0], xc[1], xc[2], xc[3]};
#pragma unroll
            for (int j = 0; j < 8; ++j) asum += fabsf(xs[j]);

            // exact 3-way truncation split, packed to bf16x2 dwords (low=even k)
            union { uint32_t u[4]; short8 v; } Ahi, Ami, Alo;
#pragma unroll
            for (int p = 0; p < 4; ++p) {
                const uint32_t b0 = __float_as_uint(xs[2 * p]);
                const uint32_t b1 = __float_as_uint(xs[2 * p + 1]);
                const uint32_t h0 = b0 & 0xFFFF0000u, h1 = b1 & 0xFFFF0000u;
                const float    t0 = xs[2 * p] - __uint_as_float(h0);
                const float    t1 = xs[2 * p + 1] - __uint_as_float(h1);
                const uint32_t m0 = __float_as_uint(t0) & 0xFFFF0000u;
                const uint32_t m1 = __float_as_uint(t1) & 0xFFFF0000u;
                const float    u0 = t0 - __uint_as_float(m0);
                const float    u1 = t1 - __uint_as_float(m1);
                const uint32_t l0 = __float_as_uint(u0) & 0xFFFF0000u;
                const uint32_t l1 = __float_as_uint(u1) & 0xFFFF0000u;
                Ahi.u[p] = h1 | (h0 >> 16);
                Ami.u[p] = m1 | (m0 >> 16);
                Alo.u[p] = l1 | (l0 >> 16);
            }
#pragma unroll
            for (int n8 = 0; n8 < 8; ++n8) {
                const short8 bf = *reinterpret_cast<const short8*>(
                    &T[(n8 * 16 + r) * TSTRIDE + (ks * 4 + g) * 8]);
                acc[n8] = __builtin_amdgcn_mfma_f32_16x16x32_bf16(Ahi.v, bf, acc[n8], 0, 0, 0);
                acc[n8] = __builtin_amdgcn_mfma_f32_16x16x32_bf16(Ami.v, bf, acc[n8], 0, 0, 0);
                acc[n8] = __builtin_amdgcn_mfma_f32_16x16x32_bf16(Alo.v, bf, acc[n8], 0, 0, 0);
            }
        }

        // A (= sum |x| of element row) reduce over k-groups, pick element e
        asum += __shfl_xor(asum, 16);
        asum += __shfl_xor(asum, 32);
        const float aElem = __shfl(asum, e);

        const size_t eg  = (size_t)(Mb + e);
        const float  bnd = aElem * EPS;
        float wkeep[2][8];

        // ---- phase 2 per rep-half hh: transpose 64 cols via wave-private pw ----
#pragma unroll
        for (int hh = 0; hh < 2; ++hh) {
            // D layout: element row = g*4+reg, col = n8*16+r (m89 mapping)
#pragma unroll
            for (int n8h = 0; n8h < 4; ++n8h) {
#pragma unroll
                for (int reg = 0; reg < 4; ++reg)
                    pw[wid][(g * 4 + reg) * PSTRIDE + n8h * 16 + r] =
                        acc[hh * 4 + n8h][reg];
            }
            // wave-local ordering: all pw writes committed before reads
            asm volatile("s_waitcnt lgkmcnt(0)" ::: "memory");

#pragma unroll
            for (int m = 0; m < 2; ++m) {
                const int ccl = c4 + 4 * m;          // chunk id within rep
                const f32x4 pa = *reinterpret_cast<const f32x4*>(
                    &pw[wid][e * PSTRIDE + ccl * 8]);
                const f32x4 pb = *reinterpret_cast<const f32x4*>(
                    &pw[wid][e * PSTRIDE + ccl * 8 + 4]);
                const float p[8] = {pa[0], pa[1], pa[2], pa[3],
                                    pb[0], pb[1], pb[2], pb[3]};
                uint32_t srp = 0, flg = 0;
#pragma unroll
                for (int j = 0; j < 8; ++j) {
                    srp |= (p[j] > 0.0f) ? (1u << j) : 0u;
                    flg |= (fabsf(p[j]) <= bnd) ? (1u << j) : 0u;
                }
                if (flg) {  // rare exact fallback: sequential fmaf, i = 0..127
                    const float* xr = x + eg * 128;
                    for (uint32_t fb = flg; fb; fb &= fb - 1) {
                        const int k = hh * 64 + ccl * 8 + __builtin_ctz(fb);
                        float s = 0.0f;
#pragma unroll
                        for (int i8 = 0; i8 < 16; ++i8) {
                            const uint4 tb = *reinterpret_cast<const uint4*>(
                                &T[k * TSTRIDE + i8 * 8]);
                            const f32x4 xA = *reinterpret_cast<const f32x4*>(xr + i8 * 8);
                            const f32x4 xB = *reinterpret_cast<const f32x4*>(xr + i8 * 8 + 4);
                            const uint32_t tu[4] = {tb.x, tb.y, tb.z, tb.w};
                            s = __builtin_fmaf(xA[0], __uint_as_float(tu[0] << 16), s);
                            s = __builtin_fmaf(xA[1], __uint_as_float(tu[0] & 0xFFFF0000u), s);
                            s = __builtin_fmaf(xA[2], __uint_as_float(tu[1] << 16), s);
                            s = __builtin_fmaf(xA[3], __uint_as_float(tu[1] & 0xFFFF0000u), s);
                            s = __builtin_fmaf(xB[0], __uint_as_float(tu[2] << 16), s);
                            s = __builtin_fmaf(xB[1], __uint_as_float(tu[2] & 0xFFFF0000u), s);
                            s = __builtin_fmaf(xB[2], __uint_as_float(tu[3] << 16), s);
                            s = __builtin_fmaf(xB[3], __uint_as_float(tu[3] & 0xFFFF0000u), s);
                        }
                        const int j = k - hh * 64 - ccl * 8;
                        srp = (srp & ~(1u << j)) | ((s > 0.0f) ? (1u << j) : 0u);
                    }
                }
                const uint64_t hhash = (HA * (uint64_t)srp + HB * (uint64_t)ccl + HC0) % PRIME;
                const uint32_t loc   = (uint32_t)hhash % RANGE + (hh ? (uint32_t)ARRAY_SZ : 0u);

                const float f0 = (float)loc;
                float* oi = out_idx + eg * 128 + hh * 64 + ccl * 8;
                *reinterpret_cast<f32x4*>(oi)     = (f32x4){f0, f0 + 1.f, f0 + 2.f, f0 + 3.f};
                *reinterpret_cast<f32x4*>(oi + 4) = (f32x4){f0 + 4.f, f0 + 5.f, f0 + 6.f, f0 + 7.f};

                float wv[8];
#pragma unroll
                for (int j = 0; j < 8; ++j) wv[j] = hw[loc + j];
                if (hh == 0) {
#pragma unroll
                    for (int j = 0; j < 8; ++j) wkeep[m][j] = wv[j];
                } else {
                    float* ov = out_val + eg * 64 + ccl * 8;
                    *reinterpret_cast<f32x4*>(ov) =
                        (f32x4){(wkeep[m][0] + wv[0]) * 0.5f, (wkeep[m][1] + wv[1]) * 0.5f,
                                (wkeep[m][2] + wv[2]) * 0.5f, (wkeep[m][3] + wv[3]) * 0.5f};
                    *reinterpret_cast<f32x4*>(ov + 4) =
                        (f32x4){(wkeep[m][4] + wv[4]) * 0.5f, (wkeep[m][5] + wv[5]) * 0.5f,
                                (wkeep[m][6] + wv[6]) * 0.5f, (wkeep[m][7] + wv[7]) * 0.5f};
                }
            }
        }
    }
}

extern "C" void kernel_launch(void* const* d_in, const int* in_sizes, int n_in,
                              void* d_out, int out_size, void* d_ws, size_t ws_size,
                              hipStream_t stream) {
    const float* x   = (const float*)d_in[0];
    const float* hw  = (const float*)d_in[1];
    const float* lsh = (const float*)d_in[2];
    const void*  rnd = (const void*)d_in[3];

    float* out_idx = (float*)d_out;
    float* out_val = out_idx + (size_t)BATCH * 128;

    lma_mfma2<<<2048, 256, 0, stream>>>(x, hw, lsh, rnd, out_idx, out_val);
}